// Round 12
// baseline (143.965 us; speedup 1.0000x reference)
//
#include <hip/hip_runtime.h>
#include <stdint.h>

// Problem constants (fixed by the reference)
#define B_IMG        64
#define M_GT         100
#define N_PROP       4000
#define K_TOT        4100          // N + M (proposal_append_gt)
#define NUM_CLASSES_ 80
#define BATCH_PER    512
#define NUM_FG_TGT   128
#define OUT_STRIDE   (B_IMG * BATCH_PER)   // 32768 elements per output tensor

#define NT           256                   // threads per block (fused kernel)
#define BPI          33                    // blocks per image (32*128 + 4)
#define EPB          128                   // elements per block (2 lanes/element)
#define FG_CAP       512                   // fg candidate capacity
#define BG_CAP       1024                  // bg candidate capacity
#define CTR_STRIDE   64                    // words between ctr[b] (256 B line)
#define CTR_BYTES    (B_IMG * CTR_STRIDE * 4)   // 16 KiB
#define NTF          1024                  // fallback kernel threads

// Key packing (uint64 compare gives exact (fg, pri, idx) descending order;
// midx rides in the low bits — idx is unique so it never affects ordering):
//   bit 50      : fg flag
//   bits 49..20 : float bits of priority (pri in [0,1) => bits < 2^30)
//   bits 19..7  : element index (0..4099 < 8192)  — reproduces the reversed-
//                 stable-argsort tiebreak (higher idx first on equal pri)
//   bits  6..0  : matched gt index (0..99 < 128)

// IoU, contraction off, BRANCHLESS: uni = area_a+area_b-inter > 0 always
// (reference boxes have wh >= 8 so both areas > 0), and inter==0 gives
// +0.0/uni = +0.0 — bit-identical to the reference's where(inter>0, ..., 0).
// Removing the select lets the compiler pipeline the div across iterations.
__device__ __forceinline__ float iou_g(float4 g,
                                       float bx1, float by1, float bx2, float by2,
                                       float area_b) {
#pragma clang fp contract(off)
    float area_a = (g.z - g.x) * (g.w - g.y);
    float ltx = fmaxf(g.x, bx1), lty = fmaxf(g.y, by1);
    float rbx = fminf(g.z, bx2), rby = fminf(g.w, by2);
    float wx = fmaxf(rbx - ltx, 0.0f);
    float wy = fmaxf(rby - lty, 0.0f);
    float inter = wx * wy;
    float uni = area_a + area_b - inter;
    return inter / uni;
}

// ---------------------------------------------------------------------------
// Fused chip-wide kernel. Grid = 64 images x 33 blocks x 256 threads.
// Phase A: 2 lanes per element — lane parity picks m in [0,50) / [50,100);
//   one __shfl_xor combines (upper half wins only on strict > == sequential
//   first-occurrence argmax). 8200 wave-chains of 50 iters (vs 4100 x 100):
//   ~8 concurrent chains/SIMD at 8 blocks/CU (16.5 KB LDS, 256 thr) — hides
//   the ~400-cycle dependent divide chain that latency-bound R4-R11.
// Handoff: coherent key stores + release fetch_add; LAST ARRIVER becomes the
//   owner (no waiting — correct under any residency/dispatch order).
// Phase B (64 owners): histogram from global keys, suffix-scan, threshold,
//   compact to LDS, O(k^2)-broadcast rank, emit DIRECT to global (prefill
//   slots [nval,512) and emit slots [0,nval) are provably disjoint).
// ---------------------------------------------------------------------------
__global__ __launch_bounds__(NT, 8) void fused_kernel(
        const float* __restrict__ gt_boxes,    // [B, M, 4]
        const float* __restrict__ prop_boxes,  // [B, N, 4]
        const int*   __restrict__ gt_classes,  // [B, M]
        const float* __restrict__ rand_pri,    // [B, K]
        uint64_t*    __restrict__ keys,        // [B, K] in ws (after ctr region)
        uint32_t*    __restrict__ ctr,         // [B*CTR_STRIDE] arrival ctrs (zeroed)
        float*       __restrict__ out)         // 5 x [B, 512] flat
{
    __shared__ float4   s_gtb4[M_GT];          // 1.6 KB
    __shared__ int      s_gtc[M_GT];           // 0.4 KB
    __shared__ int      s_hist[2][256];        // 2 KB
    __shared__ uint64_t s_cand[FG_CAP + BG_CAP]; // 12 KB: fg | bg
    __shared__ int      s_T[2], s_needed[2], s_cnt[2];
    __shared__ int      s_owner;

    const int blk = blockIdx.x;
    const int b   = blk / BPI;                 // image
    const int q   = blk % BPI;                 // slice within image
    const int tid = threadIdx.x;

    // ---- stage gt data for image b ----
    for (int i = tid; i < M_GT; i += NT) {
        s_gtb4[i] = ((const float4*)gt_boxes)[(size_t)b * M_GT + i];
        s_gtc[i]  = gt_classes[(size_t)b * M_GT + i];
    }
    __syncthreads();

    // ---- phase A: 2-lane m-split IoU argmax + key build ----
    const int e    = q * EPB + (tid >> 1);     // element id in image
    const int half = tid & 1;                  // 0: m in [0,50), 1: [50,100)
    if (e < K_TOT) {
        const uint32_t pb = __float_as_uint(rand_pri[(size_t)b * K_TOT + e]);
        float4 bp;
        if (e < N_PROP)
            bp = *(const float4*)(prop_boxes + ((size_t)b * N_PROP + e) * 4);
        else
            bp = s_gtb4[e - N_PROP];
        float area_b;
        {
#pragma clang fp contract(off)
            area_b = (bp.z - bp.x) * (bp.w - bp.y);
        }
        const int mlo = half * (M_GT / 2);
        float best = -1.0f; int bidx = mlo;
#pragma unroll 2
        for (int m = mlo; m < mlo + M_GT / 2; ++m) {
            float iv = iou_g(s_gtb4[m], bp.x, bp.y, bp.z, bp.w, area_b);
            if (iv > best) { best = iv; bidx = m; }  // strict > => first max in half
        }
        // combine halves: upper wins only on strict > (== sequential argmax)
        const float ob = __shfl_xor(best, 1);
        const int   oi = __shfl_xor(bidx, 1);
        if (half == 0) {
            if (ob > best) { best = ob; bidx = oi; }
            const bool fg = best >= 0.5f;
            uint64_t key = (fg ? (1ull << 50) : 0ull)
                         | ((uint64_t)pb << 20)
                         | ((uint64_t)e  << 7)
                         | (uint64_t)bidx;
            // coherent store: nothing dirty in L2 for the release to drain
            __hip_atomic_store(&keys[(size_t)b * K_TOT + e], key,
                               __ATOMIC_RELAXED, __HIP_MEMORY_SCOPE_AGENT);
        }
    }
    __syncthreads();

    // ---- arrival: last block of image b becomes the owner ----
    if (tid == 0) {
        uint32_t old = __hip_atomic_fetch_add(&ctr[b * CTR_STRIDE], 1u,
                                              __ATOMIC_RELEASE, __HIP_MEMORY_SCOPE_AGENT);
        s_owner = (old == (uint32_t)(BPI - 1)) ? 1 : 0;
    }
    __syncthreads();
    if (!s_owner) return;                      // non-owners exit immediately
    __builtin_amdgcn_fence(__ATOMIC_ACQUIRE, "agent");   // sync with all releases

    // ---- phase B: histogram from global keys ----
    for (int i = tid; i < 512; i += NT) s_hist[i >> 8][i & 255] = 0;
    if (tid < 2) s_cnt[tid] = 0;
    __syncthreads();
    for (int k = tid; k < K_TOT; k += NT) {
        uint64_t key = keys[(size_t)b * K_TOT + k];
        int g = ((key >> 50) & 1ull) ? 0 : 1;   // 0 = fg, 1 = bg
        uint32_t pbits = (uint32_t)((key >> 20) & 0x3FFFFFFFull);
        int bucket = min(255, (int)(__uint_as_float(pbits) * 256.0f));  // monotone
        atomicAdd(&s_hist[g][bucket], 1);
    }
    __syncthreads();

    // Hillis-Steele suffix scan (each thread owns bucket tid of both groups)
    for (int d = 1; d < 256; d <<= 1) {
        int v0 = 0, v1 = 0;
        const bool act = (tid + d < 256);
        if (act) { v0 = s_hist[0][tid + d]; v1 = s_hist[1][tid + d]; }
        __syncthreads();
        if (act) { s_hist[0][tid] += v0; s_hist[1][tid] += v1; }
        __syncthreads();
    }

    if (tid == 0) {
        int fg_total = s_hist[0][0];
        int bg_total = s_hist[1][0];
        int nfg = min(NUM_FG_TGT, fg_total);
        int nbg = min(BATCH_PER - nfg, bg_total);
        s_needed[0] = nfg; s_needed[1] = nbg;
    }
    __syncthreads();

    // bucket threshold: max t with S[t] >= need (unique crossing)
    {
        const int t = tid;
#pragma unroll
        for (int g = 0; g < 2; ++g) {
            int need = s_needed[g];
            int St  = s_hist[g][t];
            int St1 = (t == 255) ? -1 : s_hist[g][t + 1];
            if (St >= need && St1 < need) s_T[g] = t;
        }
    }
    __syncthreads();

    const int nfg = s_needed[0], nbg = s_needed[1];
    const int nval = nfg + nbg;

    // prefill: valid flag everywhere; invalid pattern only in slots [nval,512)
    // — disjoint from emit's slots [0,nval), so no write-ordering hazard.
    for (int i = tid; i < BATCH_PER; i += NT) {
        const size_t base = (size_t)b * BATCH_PER + i;
        out[4 * OUT_STRIDE + base] = (i < nval) ? 1.0f : 0.0f;
        if (i >= nval) {
            out[0 * OUT_STRIDE + base] = 0.0f;
            out[1 * OUT_STRIDE + base] = -1.0f;
            out[2 * OUT_STRIDE + base] = -1.0f;
            out[3 * OUT_STRIDE + base] = -1.0f;
        }
    }

    // compaction from global keys (L2-warm) into disjoint LDS regions
    for (int k = tid; k < K_TOT; k += NT) {
        uint64_t key = keys[(size_t)b * K_TOT + k];
        int isfg = (int)((key >> 50) & 1ull);
        uint32_t pbits = (uint32_t)((key >> 20) & 0x3FFFFFFFull);
        int bucket = min(255, (int)(__uint_as_float(pbits) * 256.0f));
        if (bucket >= s_T[isfg ? 0 : 1]) {
            if (isfg) {
                int pos = atomicAdd(&s_cnt[0], 1);
                if (pos < FG_CAP) s_cand[pos] = key;
            } else {
                int pos = atomicAdd(&s_cnt[1], 1);
                if (pos < BG_CAP) s_cand[FG_CAP + pos] = key;
            }
        }
    }
    __syncthreads();

    // rank within each group (keys unique -> each slot written exactly once,
    // independent of atomic ordering) and emit direct to global
    const int fgc = min(s_cnt[0], FG_CAP);
    const int bgc = min(s_cnt[1], BG_CAP);
    for (int c = tid; c < fgc + bgc; c += NT) {
        const bool isfg = (c < fgc);
        const int  base = isfg ? 0 : FG_CAP;
        const int  cnt  = isfg ? fgc : bgc;
        const int  ci   = isfg ? c : (c - fgc);
        const uint64_t kc = s_cand[base + ci];
        int r = 0;
        for (int j = 0; j < cnt; ++j)          // broadcast LDS reads
            r += (s_cand[base + j] > kc) ? 1 : 0;
        int slot = -1;
        if (isfg) { if (r < nfg) slot = r; }
        else      { if (r < nbg) slot = nfg + r; }
        if (slot >= 0) {
            int idx = (int)((kc >> 7) & 0x1FFFull);
            int mi  = (int)(kc & 0x7Full);
            float4 bp;
            if (idx < N_PROP)
                bp = *(const float4*)(prop_boxes + ((size_t)b * N_PROP + idx) * 4);
            else
                bp = s_gtb4[idx - N_PROP];
            float area_b;
            {
#pragma clang fp contract(off)
                area_b = (bp.z - bp.x) * (bp.w - bp.y);
            }
            // bit-exact matched_vals[idx]: same fp ops on same inputs as phase A
            float iou = iou_g(s_gtb4[mi], bp.x, bp.y, bp.z, bp.w, area_b);
            const size_t obase = (size_t)b * BATCH_PER + slot;
            out[0 * OUT_STRIDE + obase] = iou;
            out[1 * OUT_STRIDE + obase] = (float)idx;
            out[2 * OUT_STRIDE + obase] = (float)(isfg ? s_gtc[mi] : NUM_CLASSES_);
            out[3 * OUT_STRIDE + obase] = (float)mi;
        }
    }
}

// ---------------------------------------------------------------------------
// Fallback: proven single kernel (one block per image, zero workspace).
// Used only if ws_size is too small for the key buffer + counters.
// ---------------------------------------------------------------------------
__global__ __launch_bounds__(NTF) void roiheads_fallback(
        const float* __restrict__ gt_boxes,
        const float* __restrict__ prop_boxes,
        const int*   __restrict__ gt_classes,
        const float* __restrict__ rand_pri,
        float*       __restrict__ out)
{
    __shared__ uint64_t s_keys[K_TOT];
    __shared__ uint64_t s_cand[FG_CAP + BG_CAP];
    __shared__ int      s_hist[2][256];
    __shared__ float4   s_gtb4[M_GT];
    __shared__ int      s_gtc[M_GT];
    __shared__ float    s_out[5][BATCH_PER];
    __shared__ int      s_T[2], s_needed[2], s_cnt[2];

    const int b   = blockIdx.x;
    const int tid = threadIdx.x;

    for (int i = tid; i < 512; i += NTF) s_hist[i >> 8][i & 255] = 0;
    if (tid < 2) s_cnt[tid] = 0;
    for (int i = tid; i < M_GT; i += NTF) {
        s_gtb4[i] = ((const float4*)gt_boxes)[(size_t)b * M_GT + i];
        s_gtc[i]  = gt_classes[(size_t)b * M_GT + i];
    }
    __syncthreads();

    for (int k = tid; k < K_TOT; k += NTF) {
        float4 bp;
        if (k < N_PROP)
            bp = *(const float4*)(prop_boxes + ((size_t)b * N_PROP + k) * 4);
        else
            bp = s_gtb4[k - N_PROP];
        float area_b;
        {
#pragma clang fp contract(off)
            area_b = (bp.z - bp.x) * (bp.w - bp.y);
        }
        float best = -1.0f; int bidx = 0;
        for (int m = 0; m < M_GT; ++m) {
            float iv = iou_g(s_gtb4[m], bp.x, bp.y, bp.z, bp.w, area_b);
            if (iv > best) { best = iv; bidx = m; }
        }
        const bool fg = best >= 0.5f;
        const float pri = rand_pri[(size_t)b * K_TOT + k];
        const uint32_t pb = __float_as_uint(pri);
        s_keys[k] = (fg ? (1ull << 50) : 0ull)
                  | ((uint64_t)pb << 20)
                  | ((uint64_t)k  << 7)
                  | (uint64_t)bidx;
        int bucket = min(255, (int)(pri * 256.0f));
        atomicAdd(&s_hist[fg ? 0 : 1][bucket], 1);
    }
    __syncthreads();

    for (int d = 1; d < 256; d <<= 1) {
        int v = 0, g = tid >> 8, t = tid & 255;
        bool act = (tid < 512) && (t + d < 256);
        if (act) v = s_hist[g][t + d];
        __syncthreads();
        if (act) s_hist[g][t] += v;
        __syncthreads();
    }

    if (tid == 0) {
        int fg_total = s_hist[0][0];
        int bg_total = s_hist[1][0];
        int nfg = min(NUM_FG_TGT, fg_total);
        int nbg = min(BATCH_PER - nfg, bg_total);
        s_needed[0] = nfg; s_needed[1] = nbg;
    }
    __syncthreads();

    if (tid < 512) {
        int g = tid >> 8, t = tid & 255;
        int need = s_needed[g];
        int St  = s_hist[g][t];
        int St1 = (t == 255) ? -1 : s_hist[g][t + 1];
        if (St >= need && St1 < need) s_T[g] = t;
    }
    if (tid < BATCH_PER) {
        s_out[0][tid] = 0.0f; s_out[1][tid] = -1.0f;
        s_out[2][tid] = -1.0f; s_out[3][tid] = -1.0f;
    }
    __syncthreads();

    const int nfg = s_needed[0], nbg = s_needed[1];
    if (tid < BATCH_PER)
        s_out[4][tid] = (tid < nfg + nbg) ? 1.0f : 0.0f;

    for (int k = tid; k < K_TOT; k += NTF) {
        uint64_t key = s_keys[k];
        int isfg = (int)((key >> 50) & 1ull);
        uint32_t pbits = (uint32_t)((key >> 20) & 0x3FFFFFFFull);
        int bucket = min(255, (int)(__uint_as_float(pbits) * 256.0f));
        if (bucket >= s_T[isfg ? 0 : 1]) {
            if (isfg) {
                int pos = atomicAdd(&s_cnt[0], 1);
                if (pos < FG_CAP) s_cand[pos] = key;
            } else {
                int pos = atomicAdd(&s_cnt[1], 1);
                if (pos < BG_CAP) s_cand[FG_CAP + pos] = key;
            }
        }
    }
    __syncthreads();

    const int fgc = min(s_cnt[0], FG_CAP);
    const int bgc = min(s_cnt[1], BG_CAP);
    for (int c = tid; c < fgc + bgc; c += NTF) {
        const bool isfg = (c < fgc);
        const int  base = isfg ? 0 : FG_CAP;
        const int  cnt  = isfg ? fgc : bgc;
        const int  ci   = isfg ? c : (c - fgc);
        const uint64_t kc = s_cand[base + ci];
        int r = 0;
        for (int j = 0; j < cnt; ++j)
            r += (s_cand[base + j] > kc) ? 1 : 0;
        int slot = -1;
        if (isfg) { if (r < nfg) slot = r; }
        else      { if (r < nbg) slot = nfg + r; }
        if (slot >= 0) {
            int idx = (int)((kc >> 7) & 0x1FFFull);
            int mi  = (int)(kc & 0x7Full);
            float4 bp;
            if (idx < N_PROP)
                bp = *(const float4*)(prop_boxes + ((size_t)b * N_PROP + idx) * 4);
            else
                bp = s_gtb4[idx - N_PROP];
            float area_b;
            {
#pragma clang fp contract(off)
                area_b = (bp.z - bp.x) * (bp.w - bp.y);
            }
            float iou = iou_g(s_gtb4[mi], bp.x, bp.y, bp.z, bp.w, area_b);
            s_out[0][slot] = iou;
            s_out[1][slot] = (float)idx;
            s_out[2][slot] = (float)(isfg ? s_gtc[mi] : NUM_CLASSES_);
            s_out[3][slot] = (float)mi;
        }
    }
    __syncthreads();

    for (int i = tid; i < 5 * BATCH_PER; i += NTF) {
        int o = i / BATCH_PER, p = i % BATCH_PER;
        out[(size_t)o * OUT_STRIDE + (size_t)b * BATCH_PER + p] = s_out[o][p];
    }
}

extern "C" void kernel_launch(void* const* d_in, const int* in_sizes, int n_in,
                              void* d_out, int out_size, void* d_ws, size_t ws_size,
                              hipStream_t stream) {
    const float* gt_boxes   = (const float*)d_in[0];  // [64,100,4]
    const float* prop_boxes = (const float*)d_in[1];  // [64,4000,4]
    const int*   gt_classes = (const int*)  d_in[2];  // [64,100]
    const float* rand_pri   = (const float*)d_in[3];  // [64,4100]
    float* out = (float*)d_out;                       // 5 x [64,512] float32, concat

    const size_t need_ws = CTR_BYTES + (size_t)B_IMG * K_TOT * sizeof(uint64_t);
    if (d_ws != nullptr && ws_size >= need_ws) {
        uint32_t* ctr  = (uint32_t*)d_ws;
        uint64_t* keys = (uint64_t*)((char*)d_ws + CTR_BYTES);
        // zero arrival counters (captured into the graph, ordered on stream)
        hipMemsetAsync(d_ws, 0, CTR_BYTES, stream);
        fused_kernel<<<B_IMG * BPI, NT, 0, stream>>>(gt_boxes, prop_boxes,
                                                     gt_classes, rand_pri,
                                                     keys, ctr, out);
    } else {
        roiheads_fallback<<<B_IMG, NTF, 0, stream>>>(gt_boxes, prop_boxes,
                                                     gt_classes, rand_pri, out);
    }
}

// Round 13
// 102.725 us; speedup vs baseline: 1.4015x; 1.4015x over previous
//
#include <hip/hip_runtime.h>
#include <stdint.h>

// Problem constants (fixed by the reference)
#define B_IMG        64
#define M_GT         100
#define N_PROP       4000
#define K_TOT        4100          // N + M (proposal_append_gt)
#define NUM_CLASSES_ 80
#define BATCH_PER    512
#define NUM_FG_TGT   128
#define OUT_STRIDE   (B_IMG * BATCH_PER)   // 32768 elements per output tensor

// Kernel 1 (match) geometry: 2-lane m-split, 2112 blocks x 256 threads
#define NT1          256
#define BPI1         33                    // blocks per image (33*128 >= 4100)
#define EPB1         128                   // elements per block (2 lanes/elem)
// Kernel 2 (select) geometry
#define NTH          1024
#define HALF_CAP     1024
#define NTF          1024                  // fallback kernel threads

// Key packing (uint64 compare gives exact (fg, pri, idx) descending order;
// midx rides in the low bits — idx is unique so it never affects ordering):
//   bit 50      : fg flag
//   bits 49..20 : float bits of priority (pri in [0,1) => bits < 2^30)
//   bits 19..7  : element index (0..4099 < 8192)  — reproduces the reversed-
//                 stable-argsort tiebreak (higher idx first on equal pri)
//   bits  6..0  : matched gt index (0..99 < 128)

// IoU, contraction off, branchless: uni > 0 always (box wh >= 8 => areas > 0)
// and inter==0 gives +0.0/uni == +0.0 — bit-identical to the reference's
// where(inter>0, inter/uni, 0). Validated absmax-0 in R12.
__device__ __forceinline__ float iou_g(float4 g,
                                       float bx1, float by1, float bx2, float by2,
                                       float area_b) {
#pragma clang fp contract(off)
    float area_a = (g.z - g.x) * (g.w - g.y);
    float ltx = fmaxf(g.x, bx1), lty = fmaxf(g.y, by1);
    float rbx = fminf(g.z, bx2), rby = fminf(g.w, by2);
    float wx = fmaxf(rbx - ltx, 0.0f);
    float wy = fmaxf(rby - lty, 0.0f);
    float inter = wx * wy;
    float uni = area_a + area_b - inter;
    return inter / uni;
}

// ---------------------------------------------------------------------------
// Kernel 1: IoU argmax + key build. Grid = 64 x 33 blocks x 256 threads.
// 2 lanes per element (lane parity picks m in [0,50) / [50,100)); one
// __shfl_xor combines — upper half wins only on strict > == sequential
// first-occurrence argmax (validated absmax-0 in R12). 8 blocks/CU at 2 KB
// LDS => ~8 concurrent divide-chains per SIMD, C=50 — hides the ~600-cycle
// per-iteration dependent chain that latency-bound R4-R12.
// Key stores are AGENT-COHERENT: visibility to kernel 2 does not depend on
// runtime inter-kernel cache maintenance (which graph replay elides — the
// diagnosed cause of R3's replay-only divergence with plain stores).
// ---------------------------------------------------------------------------
__global__ __launch_bounds__(NT1, 8) void match_kernel(
        const float* __restrict__ gt_boxes,    // [B, M, 4]
        const float* __restrict__ prop_boxes,  // [B, N, 4]
        const float* __restrict__ rand_pri,    // [B, K]
        uint64_t*    __restrict__ keys)        // [B, K] ws
{
    __shared__ float4 s_gtb4[M_GT];            // 1.6 KB

    const int blk = blockIdx.x;
    const int b   = blk / BPI1;                // image
    const int q   = blk % BPI1;                // slice
    const int tid = threadIdx.x;

    for (int i = tid; i < M_GT; i += NT1)
        s_gtb4[i] = ((const float4*)gt_boxes)[(size_t)b * M_GT + i];
    __syncthreads();

    const int e    = q * EPB1 + (tid >> 1);    // element id in image
    const int half = tid & 1;                  // 0: m in [0,50), 1: [50,100)
    if (e >= K_TOT) return;

    const uint32_t pb = __float_as_uint(rand_pri[(size_t)b * K_TOT + e]);
    float4 bp;
    if (e < N_PROP)
        bp = *(const float4*)(prop_boxes + ((size_t)b * N_PROP + e) * 4);
    else
        bp = s_gtb4[e - N_PROP];
    float area_b;
    {
#pragma clang fp contract(off)
        area_b = (bp.z - bp.x) * (bp.w - bp.y);
    }
    const int mlo = half * (M_GT / 2);
    float best = -1.0f; int bidx = mlo;
#pragma unroll 2
    for (int m = mlo; m < mlo + M_GT / 2; ++m) {
        float iv = iou_g(s_gtb4[m], bp.x, bp.y, bp.z, bp.w, area_b);
        if (iv > best) { best = iv; bidx = m; }    // strict > => first max in half
    }
    // combine halves: upper wins only on strict > (== sequential argmax)
    const float ob = __shfl_xor(best, 1);
    const int   oi = __shfl_xor(bidx, 1);
    if (half == 0) {
        if (ob > best) { best = ob; bidx = oi; }
        const bool fg = best >= 0.5f;
        uint64_t key = (fg ? (1ull << 50) : 0ull)
                     | ((uint64_t)pb << 20)
                     | ((uint64_t)e  << 7)
                     | (uint64_t)bidx;
        __hip_atomic_store(&keys[(size_t)b * K_TOT + e], key,
                           __ATOMIC_RELAXED, __HIP_MEMORY_SCOPE_AGENT);
    }
}

// ---------------------------------------------------------------------------
// Kernel 2: exact top-k select + rank + emit. Grid = 64 blocks x 1024 thr.
// Entry acquire fence invalidates any stale L1/L2 lines this XCD cached in a
// previous graph replay (keys were written coherently by kernel 1; the graph
// edge orders execution). Then R11's proven phase B verbatim.
// ---------------------------------------------------------------------------
__global__ __launch_bounds__(NTH) void select_kernel(
        const float* __restrict__ gt_boxes,    // [B, M, 4]
        const float* __restrict__ prop_boxes,  // [B, N, 4]
        const int*   __restrict__ gt_classes,  // [B, M]
        const uint64_t* __restrict__ keys,     // [B, K] ws
        float*       __restrict__ out)         // 5 x [B, 512] flat
{
    __shared__ uint64_t s_keys[K_TOT];         // 32.8 KB
    __shared__ uint64_t s_cand[2 * HALF_CAP];  // 16 KB: fg half | bg half
    __shared__ int      s_hist[2][256];        // 2 KB
    __shared__ float4   s_gtb4[M_GT];
    __shared__ int      s_gtc[M_GT];
    __shared__ float    s_out[5][BATCH_PER];   // 10 KB staging
    __shared__ int      s_T[2], s_needed[2], s_cnt[2];

    const int b   = blockIdx.x;
    const int tid = threadIdx.x;

    __builtin_amdgcn_fence(__ATOMIC_ACQUIRE, "agent");  // drop stale cache lines

    for (int i = tid; i < 512; i += NTH) s_hist[i >> 8][i & 255] = 0;
    if (tid < 2) s_cnt[tid] = 0;
    for (int i = tid; i < M_GT; i += NTH) {
        s_gtb4[i] = ((const float4*)gt_boxes)[(size_t)b * M_GT + i];
        s_gtc[i]  = gt_classes[(size_t)b * M_GT + i];
    }
    __syncthreads();

    // stage keys + histogram per group
    for (int k = tid; k < K_TOT; k += NTH) {
        uint64_t key = keys[(size_t)b * K_TOT + k];
        s_keys[k] = key;
        int g = ((key >> 50) & 1ull) ? 0 : 1;   // 0 = fg, 1 = bg
        uint32_t pbits = (uint32_t)((key >> 20) & 0x3FFFFFFFull);
        int bucket = min(255, (int)(__uint_as_float(pbits) * 256.0f));  // monotone
        atomicAdd(&s_hist[g][bucket], 1);
    }
    __syncthreads();

    // Hillis-Steele suffix scan over each 256-bucket histogram
    for (int d = 1; d < 256; d <<= 1) {
        int v = 0, g = tid >> 8, t = tid & 255;
        bool act = (tid < 512) && (t + d < 256);
        if (act) v = s_hist[g][t + d];
        __syncthreads();
        if (act) s_hist[g][t] += v;
        __syncthreads();
    }

    if (tid == 0) {
        int fg_total = s_hist[0][0];
        int bg_total = s_hist[1][0];
        int nfg = min(NUM_FG_TGT, fg_total);
        int nbg = min(BATCH_PER - nfg, bg_total);
        s_needed[0] = nfg; s_needed[1] = nbg;
    }
    __syncthreads();

    // bucket threshold: max t with S[t] >= need (unique crossing)
    if (tid < 512) {
        int g = tid >> 8, t = tid & 255;
        int need = s_needed[g];
        int St  = s_hist[g][t];
        int St1 = (t == 255) ? -1 : s_hist[g][t + 1];
        if (St >= need && St1 < need) s_T[g] = t;
    }
    if (tid < BATCH_PER) {                     // prefill invalid pattern
        s_out[0][tid] = 0.0f; s_out[1][tid] = -1.0f;
        s_out[2][tid] = -1.0f; s_out[3][tid] = -1.0f;
    }
    __syncthreads();

    const int nfg = s_needed[0], nbg = s_needed[1];
    if (tid < BATCH_PER)
        s_out[4][tid] = (tid < nfg + nbg) ? 1.0f : 0.0f;

    // compaction into disjoint halves (fg -> [0,HALF_CAP), bg -> [HALF_CAP,...))
    for (int k = tid; k < K_TOT; k += NTH) {
        uint64_t key = s_keys[k];
        int g = ((key >> 50) & 1ull) ? 0 : 1;
        uint32_t pbits = (uint32_t)((key >> 20) & 0x3FFFFFFFull);
        int bucket = min(255, (int)(__uint_as_float(pbits) * 256.0f));
        if (bucket >= s_T[g]) {
            int pos = atomicAdd(&s_cnt[g], 1);
            if (pos < HALF_CAP) s_cand[g * HALF_CAP + pos] = key;
        }
    }
    __syncthreads();

    // rank within each half (keys unique -> each slot written exactly once,
    // independent of atomic ordering) and emit
    const int fgc = min(s_cnt[0], HALF_CAP);
    const int bgc = min(s_cnt[1], HALF_CAP);
    for (int c = tid; c < fgc + bgc; c += NTH) {
        const bool isfg = (c < fgc);
        const int  base = isfg ? 0 : HALF_CAP;
        const int  cnt  = isfg ? fgc : bgc;
        const int  ci   = isfg ? c : (c - fgc);
        const uint64_t kc = s_cand[base + ci];
        int r = 0;
        for (int j = 0; j < cnt; ++j)          // broadcast LDS reads
            r += (s_cand[base + j] > kc) ? 1 : 0;
        int slot = -1;
        if (isfg) { if (r < nfg) slot = r; }
        else      { if (r < nbg) slot = nfg + r; }
        if (slot >= 0) {
            int idx = (int)((kc >> 7) & 0x1FFFull);
            int mi  = (int)(kc & 0x7Full);
            float4 bp;
            if (idx < N_PROP)
                bp = *(const float4*)(prop_boxes + ((size_t)b * N_PROP + idx) * 4);
            else
                bp = s_gtb4[idx - N_PROP];
            float area_b;
            {
#pragma clang fp contract(off)
                area_b = (bp.z - bp.x) * (bp.w - bp.y);
            }
            // bit-exact matched_vals[idx]: same fp ops on same inputs as K1
            float iou = iou_g(s_gtb4[mi], bp.x, bp.y, bp.z, bp.w, area_b);
            s_out[0][slot] = iou;
            s_out[1][slot] = (float)idx;
            s_out[2][slot] = (float)(isfg ? s_gtc[mi] : NUM_CLASSES_);
            s_out[3][slot] = (float)mi;
        }
    }
    __syncthreads();

    // coalesced write-out
    for (int i = tid; i < 5 * BATCH_PER; i += NTH) {
        int o = i / BATCH_PER, p = i % BATCH_PER;
        out[(size_t)o * OUT_STRIDE + (size_t)b * BATCH_PER + p] = s_out[o][p];
    }
}

// ---------------------------------------------------------------------------
// Fallback: proven single kernel (one block per image, zero workspace).
// Used only if ws_size is too small for the key buffer.
// ---------------------------------------------------------------------------
__global__ __launch_bounds__(NTF) void roiheads_fallback(
        const float* __restrict__ gt_boxes,
        const float* __restrict__ prop_boxes,
        const int*   __restrict__ gt_classes,
        const float* __restrict__ rand_pri,
        float*       __restrict__ out)
{
    __shared__ uint64_t s_keys[K_TOT];
    __shared__ uint64_t s_cand[2 * HALF_CAP];
    __shared__ int      s_hist[2][256];
    __shared__ float4   s_gtb4[M_GT];
    __shared__ int      s_gtc[M_GT];
    __shared__ float    s_out[5][BATCH_PER];
    __shared__ int      s_T[2], s_needed[2], s_cnt[2];

    const int b   = blockIdx.x;
    const int tid = threadIdx.x;

    for (int i = tid; i < 512; i += NTF) s_hist[i >> 8][i & 255] = 0;
    if (tid < 2) s_cnt[tid] = 0;
    for (int i = tid; i < M_GT; i += NTF) {
        s_gtb4[i] = ((const float4*)gt_boxes)[(size_t)b * M_GT + i];
        s_gtc[i]  = gt_classes[(size_t)b * M_GT + i];
    }
    __syncthreads();

    for (int k = tid; k < K_TOT; k += NTF) {
        float4 bp;
        if (k < N_PROP)
            bp = *(const float4*)(prop_boxes + ((size_t)b * N_PROP + k) * 4);
        else
            bp = s_gtb4[k - N_PROP];
        float area_b;
        {
#pragma clang fp contract(off)
            area_b = (bp.z - bp.x) * (bp.w - bp.y);
        }
        float best = -1.0f; int bidx = 0;
        for (int m = 0; m < M_GT; ++m) {
            float iv = iou_g(s_gtb4[m], bp.x, bp.y, bp.z, bp.w, area_b);
            if (iv > best) { best = iv; bidx = m; }
        }
        const bool fg = best >= 0.5f;
        const float pri = rand_pri[(size_t)b * K_TOT + k];
        const uint32_t pb = __float_as_uint(pri);
        s_keys[k] = (fg ? (1ull << 50) : 0ull)
                  | ((uint64_t)pb << 20)
                  | ((uint64_t)k  << 7)
                  | (uint64_t)bidx;
        int bucket = min(255, (int)(pri * 256.0f));
        atomicAdd(&s_hist[fg ? 0 : 1][bucket], 1);
    }
    __syncthreads();

    for (int d = 1; d < 256; d <<= 1) {
        int v = 0, g = tid >> 8, t = tid & 255;
        bool act = (tid < 512) && (t + d < 256);
        if (act) v = s_hist[g][t + d];
        __syncthreads();
        if (act) s_hist[g][t] += v;
        __syncthreads();
    }

    if (tid == 0) {
        int fg_total = s_hist[0][0];
        int bg_total = s_hist[1][0];
        int nfg = min(NUM_FG_TGT, fg_total);
        int nbg = min(BATCH_PER - nfg, bg_total);
        s_needed[0] = nfg; s_needed[1] = nbg;
    }
    __syncthreads();

    if (tid < 512) {
        int g = tid >> 8, t = tid & 255;
        int need = s_needed[g];
        int St  = s_hist[g][t];
        int St1 = (t == 255) ? -1 : s_hist[g][t + 1];
        if (St >= need && St1 < need) s_T[g] = t;
    }
    if (tid < BATCH_PER) {
        s_out[0][tid] = 0.0f; s_out[1][tid] = -1.0f;
        s_out[2][tid] = -1.0f; s_out[3][tid] = -1.0f;
    }
    __syncthreads();

    const int nfg = s_needed[0], nbg = s_needed[1];
    if (tid < BATCH_PER)
        s_out[4][tid] = (tid < nfg + nbg) ? 1.0f : 0.0f;

    for (int k = tid; k < K_TOT; k += NTF) {
        uint64_t key = s_keys[k];
        int g = ((key >> 50) & 1ull) ? 0 : 1;
        uint32_t pbits = (uint32_t)((key >> 20) & 0x3FFFFFFFull);
        int bucket = min(255, (int)(__uint_as_float(pbits) * 256.0f));
        if (bucket >= s_T[g]) {
            int pos = atomicAdd(&s_cnt[g], 1);
            if (pos < HALF_CAP) s_cand[g * HALF_CAP + pos] = key;
        }
    }
    __syncthreads();

    const int fgc = min(s_cnt[0], HALF_CAP);
    const int bgc = min(s_cnt[1], HALF_CAP);
    for (int c = tid; c < fgc + bgc; c += NTF) {
        const bool isfg = (c < fgc);
        const int  base = isfg ? 0 : HALF_CAP;
        const int  cnt  = isfg ? fgc : bgc;
        const int  ci   = isfg ? c : (c - fgc);
        const uint64_t kc = s_cand[base + ci];
        int r = 0;
        for (int j = 0; j < cnt; ++j)
            r += (s_cand[base + j] > kc) ? 1 : 0;
        int slot = -1;
        if (isfg) { if (r < nfg) slot = r; }
        else      { if (r < nbg) slot = nfg + r; }
        if (slot >= 0) {
            int idx = (int)((kc >> 7) & 0x1FFFull);
            int mi  = (int)(kc & 0x7Full);
            float4 bp;
            if (idx < N_PROP)
                bp = *(const float4*)(prop_boxes + ((size_t)b * N_PROP + idx) * 4);
            else
                bp = s_gtb4[idx - N_PROP];
            float area_b;
            {
#pragma clang fp contract(off)
                area_b = (bp.z - bp.x) * (bp.w - bp.y);
            }
            float iou = iou_g(s_gtb4[mi], bp.x, bp.y, bp.z, bp.w, area_b);
            s_out[0][slot] = iou;
            s_out[1][slot] = (float)idx;
            s_out[2][slot] = (float)(isfg ? s_gtc[mi] : NUM_CLASSES_);
            s_out[3][slot] = (float)mi;
        }
    }
    __syncthreads();

    for (int i = tid; i < 5 * BATCH_PER; i += NTF) {
        int o = i / BATCH_PER, p = i % BATCH_PER;
        out[(size_t)o * OUT_STRIDE + (size_t)b * BATCH_PER + p] = s_out[o][p];
    }
}

extern "C" void kernel_launch(void* const* d_in, const int* in_sizes, int n_in,
                              void* d_out, int out_size, void* d_ws, size_t ws_size,
                              hipStream_t stream) {
    const float* gt_boxes   = (const float*)d_in[0];  // [64,100,4]
    const float* prop_boxes = (const float*)d_in[1];  // [64,4000,4]
    const int*   gt_classes = (const int*)  d_in[2];  // [64,100]
    const float* rand_pri   = (const float*)d_in[3];  // [64,4100]
    float* out = (float*)d_out;                       // 5 x [64,512] float32, concat

    const size_t need_ws = (size_t)B_IMG * K_TOT * sizeof(uint64_t);  // 2.1 MB
    if (d_ws != nullptr && ws_size >= need_ws) {
        uint64_t* keys = (uint64_t*)d_ws;
        match_kernel<<<B_IMG * BPI1, NT1, 0, stream>>>(gt_boxes, prop_boxes,
                                                       rand_pri, keys);
        select_kernel<<<B_IMG, NTH, 0, stream>>>(gt_boxes, prop_boxes,
                                                 gt_classes, keys, out);
    } else {
        roiheads_fallback<<<B_IMG, NTF, 0, stream>>>(gt_boxes, prop_boxes,
                                                     gt_classes, rand_pri, out);
    }
}